// Round 8
// baseline (231.497 us; speedup 1.0000x reference)
//
#include <hip/hip_runtime.h>

// CIN (xDeepFM) fully-fused kernel for MI355X.
// B=4096, F=32, D=32; layer1: K1=1024 -> N=128; layer2: K2=4096 -> N=128.
// GEMM rows=(b,d); A generated in registers: A[(b,d)][h*M+m] = x0[b,h,d]*prev[b,m,d].
// mfma_f32_32x32x16_f16.
// R8: wave tile halved to 2 b x 32 cols (acc 32 AGPR, ~82 regs/wave) so
// 6 waves/SIMD fit (was 4, reg-capped). Block = 2 b x 128 cols, LDS 20 KB,
// grid 2048. Theory: plateau at ~150us was TLP-starvation (Occupancy ~33%,
// register exact-fit) -- all ILP/scheduling levers were neutral R3-R7.

typedef _Float16 half_t;
typedef _Float16 half4v __attribute__((ext_vector_type(4)));
typedef _Float16 half8 __attribute__((ext_vector_type(8)));
typedef float f32x16 __attribute__((ext_vector_type(16)));

// ---- W pack (both filters, one launch): Wp[s][tg][n][8], k=h*M+mc*16+tg*8+j.
__global__ void prep_w_kernel(const float* __restrict__ W0,
                              const float* __restrict__ W1,
                              half_t* __restrict__ Wp0,
                              half_t* __restrict__ Wp1) {
  int gid = blockIdx.x * 256 + threadIdx.x;  // 320*256 threads
  int n = gid & 127;
  int tg = (gid >> 7) & 1;
  int s = gid >> 8;  // 0..319
  const float* W;
  half_t* Wp;
  int M, sl;
  if (s < 64) { W = W0; Wp = Wp0; M = 32; sl = s; }
  else        { W = W1; Wp = Wp1; M = 128; sl = s - 64; }
  int h = sl & 31, mc = sl >> 5;
  int kbase = h * M + mc * 16 + tg * 8;
  half8 v;
#pragma unroll
  for (int j = 0; j < 8; ++j) v[j] = (half_t)W[(size_t)(kbase + j) * 128 + n];
  *(half8*)(Wp + ((size_t)(sl * 2 + tg) * 128 + n) * 8) = v;
}

// swizzled prevT index: logical (row, m) -> halfs offset. 16B-chunk XOR spread.
__device__ __forceinline__ int pswz(int row, int m) {
  return row * 128 + (((m >> 3) ^ (row & 15)) << 3) + (m & 7);
}

__device__ __forceinline__ f32x16 mfma3216(half8 a, half8 b, f32x16 c) {
  return __builtin_amdgcn_mfma_f32_32x32x16_f16(a, b, c, 0, 0, 0);
}

// One CIN layer: MC m-chunks x 32 h. gg unrolled x2 with ping(a)/pong(b)
// register sets (zero rotation movs). x via ds_read_b64: xq4[rt*2 + (h&1)].
template <int MC, bool L1>
__device__ __forceinline__ void layer_loop(const half_t* __restrict__ Wp,
                                           const half_t* __restrict__ psrc,
                                           const half_t* __restrict__ xrd,
                                           int woff, int l31, int hi,
                                           f32x16 acc[2]) {
  // preload gg=0 (ping: s=0,1) and gg=1 (pong: s=2,3)
  half8 B0a = *(const half8*)(Wp + 0 * 2048 + woff);
  half8 B1a = *(const half8*)(Wp + 1 * 2048 + woff);
  half8 B0b = *(const half8*)(Wp + 2 * 2048 + woff);
  half8 B1b = *(const half8*)(Wp + 3 * 2048 + woff);
  half4v xqa = *(const half4v*)(xrd);          // hp=0: h=0,1
  half4v xqb = *(const half4v*)(xrd + 128);    // hp=1: h=2,3

  half8 P[2];
#pragma unroll
  for (int rt = 0; rt < 2; ++rt)
    P[rt] = L1 ? *(const half8*)&psrc[(rt * 32 + l31) * 40 + hi * 8]
               : *(const half8*)&psrc[pswz(rt * 32 + l31, hi * 8)];

#pragma unroll 1
  for (int mc = 0; mc < MC; ++mc) {
#pragma unroll 1
    for (int p = 0; p < 8; ++p) {
      const int g0 = mc * 16 + 2 * p;  // even gg (global)
      // ---- even gg (h = 4p, 4p+1): consume ping ----
#pragma unroll
      for (int rt = 0; rt < 2; ++rt)
        acc[rt] = mfma3216(P[rt] * xqa[rt * 2 + 0], B0a, acc[rt]);
#pragma unroll
      for (int rt = 0; rt < 2; ++rt)
        acc[rt] = mfma3216(P[rt] * xqa[rt * 2 + 1], B1a, acc[rt]);
      {  // refill ping for g0+2
        const int sn = (2 * (g0 + 2)) & (MC * 32 - 1);
        B0a = *(const half8*)(Wp + (size_t)sn * 2048 + woff);
        B1a = *(const half8*)(Wp + (size_t)(sn + 1) * 2048 + woff);
        xqa = *(const half4v*)(xrd + ((2 * p + 2) & 15) * 128);
      }
      // ---- odd gg (h = 4p+2, 4p+3): consume pong ----
#pragma unroll
      for (int rt = 0; rt < 2; ++rt)
        acc[rt] = mfma3216(P[rt] * xqb[rt * 2 + 0], B0b, acc[rt]);
#pragma unroll
      for (int rt = 0; rt < 2; ++rt)
        acc[rt] = mfma3216(P[rt] * xqb[rt * 2 + 1], B1b, acc[rt]);
      {  // refill pong for g0+3
        const int sn = (2 * (g0 + 3)) & (MC * 32 - 1);
        B0b = *(const half8*)(Wp + (size_t)sn * 2048 + woff);
        B1b = *(const half8*)(Wp + (size_t)(sn + 1) * 2048 + woff);
        xqb = *(const half4v*)(xrd + ((2 * p + 3) & 15) * 128);
      }
    }
    if (mc + 1 < MC) {
      const int mn = (mc + 1) * 16;
#pragma unroll
      for (int rt = 0; rt < 2; ++rt)
        P[rt] = L1 ? *(const half8*)&psrc[(rt * 32 + l31) * 40 + mn + hi * 8]
                   : *(const half8*)&psrc[pswz(rt * 32 + l31, mn + hi * 8)];
    }
  }
}

__global__ __launch_bounds__(256, 6) void cin_fused_kernel(
    const float* __restrict__ x0,    // [4096][32][32] fp32
    const half_t* __restrict__ Wp0,  // 64*2048 halfs
    const half_t* __restrict__ Wp1,  // 256*2048 halfs
    float* __restrict__ out) {       // [4096][256]
  __shared__ half_t xsf3[16 * 128];      // [h>>1][d][bi][h&1], 2 b (4 KB)
  __shared__ half_t prevT[2 * 32 * 128]; // swizzled [bi][d][m] (16 KB); alias xT
  half_t* xT = prevT;                    // [bi*32+d][h], stride 40 halfs

  const int tid = threadIdx.x;
  const int b0 = blockIdx.x * 2;

  // ---- stage x0 -> xsf3 and xT (2 b = 2048 floats = 512 float4) ----
  const float4* x4 = (const float4*)(x0 + (size_t)b0 * 1024);
#pragma unroll
  for (int r = 0; r < 2; ++r) {
    int q = r * 256 + tid;
    float4 v = x4[q];
    int e = q * 4;
    int bi = e >> 10, h = (e >> 5) & 31, d0 = e & 31;
    half4v hv = {(half_t)v.x, (half_t)v.y, (half_t)v.z, (half_t)v.w};
#pragma unroll
    for (int j = 0; j < 4; ++j) {
      xsf3[(h >> 1) * 128 + (d0 + j) * 4 + bi * 2 + (h & 1)] = hv[j];
      xT[(bi * 32 + d0 + j) * 40 + h] = hv[j];
    }
  }
  __syncthreads();

  const int lane = tid & 63;
  const int l31 = lane & 31;
  const int hi = lane >> 5;
  const int wave = tid >> 6;
  const int n0 = wave * 32;

  const int woff = hi * 1024 + (n0 + l31) * 8;  // per-lane B offset (halfs)
  const half_t* xrd = &xsf3[l31 * 4];           // + hp*128 halfs

  f32x16 acc[2];
#pragma unroll
  for (int rt = 0; rt < 2; ++rt)
#pragma unroll
    for (int r = 0; r < 16; ++r) acc[rt][r] = 0.f;

  // ================= layer 1 =================
  layer_loop<2, true>(Wp0, xT, xrd, woff, l31, hi, acc);

  __syncthreads();  // all waves done reading xT before prevT overwrite

  // ---- epilogue 1: relu, cur1 -> prevT (swizzled), d-sum -> out[:, 0:128] ----
#pragma unroll
  for (int rt = 0; rt < 2; ++rt) {
    float s = 0.f;
#pragma unroll
    for (int r = 0; r < 16; ++r) {
      float v = acc[rt][r];
      v = v > 0.f ? v : 0.f;
      s += v;
      int d = (r & 3) + ((r >> 2) << 3) + hi * 4;  // C/D row map (32x32)
      prevT[pswz(rt * 32 + d, n0 + l31)] = (half_t)v;
      acc[rt][r] = 0.f;
    }
    s += __shfl_down(s, 32);
    if (lane < 32) out[(size_t)(b0 + rt) * 256 + n0 + lane] = s;
  }
  __syncthreads();

  // ================= layer 2 =================
  layer_loop<8, false>(Wp1, prevT, xrd, woff, l31, hi, acc);

  // ---- epilogue 2: relu, d-sum -> out[:, 128:256] ----
#pragma unroll
  for (int rt = 0; rt < 2; ++rt) {
    float s = 0.f;
#pragma unroll
    for (int r = 0; r < 16; ++r) {
      float v = acc[rt][r];
      s += v > 0.f ? v : 0.f;
    }
    s += __shfl_down(s, 32);
    if (lane < 32) out[(size_t)(b0 + rt) * 256 + 128 + n0 + lane] = s;
  }
}

extern "C" void kernel_launch(void* const* d_in, const int* in_sizes, int n_in,
                              void* d_out, int out_size, void* d_ws,
                              size_t ws_size, hipStream_t stream) {
  const float* x0 = (const float*)d_in[0];  // [4096,32,32]
  const float* w0 = (const float*)d_in[1];  // [1,1024,128]
  const float* w1 = (const float*)d_in[2];  // [1,4096,128]
  float* out = (float*)d_out;               // [4096,256]
  char* ws = (char*)d_ws;

  half_t* Wp0 = (half_t*)(ws);                  // 64*2048 f16 = 256 KB
  half_t* Wp1 = (half_t*)(ws + 64 * 2048 * 2);  // 256*2048 f16 = 1 MB

  hipLaunchKernelGGL(prep_w_kernel, dim3(320), dim3(256), 0, stream, w0, w1,
                     Wp0, Wp1);
  hipLaunchKernelGGL(cin_fused_kernel, dim3(2048), dim3(256), 0, stream, x0,
                     Wp0, Wp1, out);
}

// Round 9
// 200.677 us; speedup vs baseline: 1.1536x; 1.1536x over previous
//
#include <hip/hip_runtime.h>

// CIN (xDeepFM) fully-fused kernel for MI355X.
// B=4096, F=32, D=32; layer1: K1=1024 -> N=128; layer2: K2=4096 -> N=128.
// GEMM rows=(b,d); A generated in registers: A[(b,d)][h*M+m] = x0[b,h,d]*prev[b,m,d].
// mfma_f32_32x32x16_f16.
// R9: fat wave = 8 b x 32 cols (acc 128 AGPR, ~230 regs, 2 waves/SIMD).
// One B-load pair now feeds 16 MFMAs (B-bytes/MFMA halved vs R5, quartered
// vs R8). Theory: plateau tracks B-operand delivery (Wp stream through
// L1/L2), evidenced by R8 regressing when B/MFMA doubled.

typedef _Float16 half_t;
typedef _Float16 half4v __attribute__((ext_vector_type(4)));
typedef _Float16 half8 __attribute__((ext_vector_type(8)));
typedef float f32x16 __attribute__((ext_vector_type(16)));

// ---- W pack (both filters, one launch): Wp[s][tg][n][8], k=h*M+mc*16+tg*8+j.
__global__ void prep_w_kernel(const float* __restrict__ W0,
                              const float* __restrict__ W1,
                              half_t* __restrict__ Wp0,
                              half_t* __restrict__ Wp1) {
  int gid = blockIdx.x * 256 + threadIdx.x;  // 320*256 threads
  int n = gid & 127;
  int tg = (gid >> 7) & 1;
  int s = gid >> 8;  // 0..319
  const float* W;
  half_t* Wp;
  int M, sl;
  if (s < 64) { W = W0; Wp = Wp0; M = 32; sl = s; }
  else        { W = W1; Wp = Wp1; M = 128; sl = s - 64; }
  int h = sl & 31, mc = sl >> 5;
  int kbase = h * M + mc * 16 + tg * 8;
  half8 v;
#pragma unroll
  for (int j = 0; j < 8; ++j) v[j] = (half_t)W[(size_t)(kbase + j) * 128 + n];
  *(half8*)(Wp + ((size_t)(sl * 2 + tg) * 128 + n) * 8) = v;
}

// swizzled prevT index: logical (row, m) -> halfs offset. 16B-chunk XOR spread.
__device__ __forceinline__ int pswz(int row, int m) {
  return row * 128 + (((m >> 3) ^ (row & 15)) << 3) + (m & 7);
}

__device__ __forceinline__ f32x16 mfma3216(half8 a, half8 b, f32x16 c) {
  return __builtin_amdgcn_mfma_f32_32x32x16_f16(a, b, c, 0, 0, 0);
}

// One CIN layer: MC m-chunks x 32 h. B depth-2 ping-pong (register-renamed);
// x read per p-iter (4x ds_read_b128 at body top, consumed across 32 MFMAs).
// xAl/xBl: lane-based pointers, stride 256 halfs per h-pair.
template <int MC, bool L1>
__device__ __forceinline__ void layer_loop(const half_t* __restrict__ Wp,
                                           const half_t* __restrict__ psrc,
                                           const half_t* __restrict__ xAl,
                                           const half_t* __restrict__ xBl,
                                           int woff, int l31, int hi,
                                           f32x16 acc[8]) {
  half8 B0a = *(const half8*)(Wp + 0 * 2048 + woff);
  half8 B1a = *(const half8*)(Wp + 1 * 2048 + woff);
  half8 B0b = *(const half8*)(Wp + 2 * 2048 + woff);
  half8 B1b = *(const half8*)(Wp + 3 * 2048 + woff);

  half8 P[8];
#pragma unroll
  for (int rt = 0; rt < 8; ++rt)
    P[rt] = L1 ? *(const half8*)&psrc[(rt * 32 + l31) * 40 + hi * 8]
               : *(const half8*)&psrc[pswz(rt * 32 + l31, hi * 8)];

#pragma unroll 1
  for (int mc = 0; mc < MC; ++mc) {
#pragma unroll 1
    for (int p = 0; p < 8; ++p) {
      const int g0 = mc * 16 + 2 * p;  // even gg (global)
      // x for this p-iter: even gg uses hp=2p, odd uses 2p+1
      half8 xLa = *(const half8*)(xAl + (2 * p) * 256);
      half8 xHa = *(const half8*)(xBl + (2 * p) * 256);
      half8 xLb = *(const half8*)(xAl + (2 * p + 1) * 256);
      half8 xHb = *(const half8*)(xBl + (2 * p + 1) * 256);
      // ---- even gg: consume ping ----
#pragma unroll
      for (int rt = 0; rt < 8; ++rt) {
        half_t xv = (rt < 4) ? xLa[(rt & 3) * 2 + 0] : xHa[(rt & 3) * 2 + 0];
        acc[rt] = mfma3216(P[rt] * xv, B0a, acc[rt]);
      }
#pragma unroll
      for (int rt = 0; rt < 8; ++rt) {
        half_t xv = (rt < 4) ? xLa[(rt & 3) * 2 + 1] : xHa[(rt & 3) * 2 + 1];
        acc[rt] = mfma3216(P[rt] * xv, B1a, acc[rt]);
      }
      {  // refill ping for g0+2
        const int sn = (2 * (g0 + 2)) & (MC * 32 - 1);
        B0a = *(const half8*)(Wp + (size_t)sn * 2048 + woff);
        B1a = *(const half8*)(Wp + (size_t)(sn + 1) * 2048 + woff);
      }
      // ---- odd gg: consume pong ----
#pragma unroll
      for (int rt = 0; rt < 8; ++rt) {
        half_t xv = (rt < 4) ? xLb[(rt & 3) * 2 + 0] : xHb[(rt & 3) * 2 + 0];
        acc[rt] = mfma3216(P[rt] * xv, B0b, acc[rt]);
      }
#pragma unroll
      for (int rt = 0; rt < 8; ++rt) {
        half_t xv = (rt < 4) ? xLb[(rt & 3) * 2 + 1] : xHb[(rt & 3) * 2 + 1];
        acc[rt] = mfma3216(P[rt] * xv, B1b, acc[rt]);
      }
      {  // refill pong for g0+3
        const int sn = (2 * (g0 + 3)) & (MC * 32 - 1);
        B0b = *(const half8*)(Wp + (size_t)sn * 2048 + woff);
        B1b = *(const half8*)(Wp + (size_t)(sn + 1) * 2048 + woff);
      }
    }
    if (mc + 1 < MC) {
      const int mn = (mc + 1) * 16;
#pragma unroll
      for (int rt = 0; rt < 8; ++rt)
        P[rt] = L1 ? *(const half8*)&psrc[(rt * 32 + l31) * 40 + mn + hi * 8]
                   : *(const half8*)&psrc[pswz(rt * 32 + l31, mn + hi * 8)];
    }
  }
}

__global__ __launch_bounds__(256, 2) void cin_fused_kernel(
    const float* __restrict__ x0,    // [4096][32][32] fp32
    const half_t* __restrict__ Wp0,  // 64*2048 halfs
    const half_t* __restrict__ Wp1,  // 256*2048 halfs
    float* __restrict__ out) {       // [4096][256]
  __shared__ half_t xA[16 * 32 * 8];      // [hp][d][bi(0-3)*2+(h&1)] (8 KB)
  __shared__ half_t xB[16 * 32 * 8];      // bi 4-7 (8 KB)
  __shared__ half_t prevT[8 * 32 * 128];  // swizzled [bi][d][m] (64 KB); alias xT
  half_t* xT = prevT;                     // [bi*32+d][h], stride 40 halfs

  const int tid = threadIdx.x;
  const int b0 = blockIdx.x * 8;

  // ---- stage x0 -> xA/xB and xT (8 b = 8192 floats = 2048 float4) ----
  const float4* x4 = (const float4*)(x0 + (size_t)b0 * 1024);
#pragma unroll
  for (int r = 0; r < 8; ++r) {
    int q = r * 256 + tid;
    float4 v = x4[q];
    int e4 = q * 4;
    int bi = e4 >> 10, h = (e4 >> 5) & 31, d0 = e4 & 31;
    half4v hv = {(half_t)v.x, (half_t)v.y, (half_t)v.z, (half_t)v.w};
    half_t* xdst = (bi < 4) ? xA : xB;
    const int bl = bi & 3;
#pragma unroll
    for (int j = 0; j < 4; ++j) {
      xdst[((h >> 1) * 32 + d0 + j) * 8 + bl * 2 + (h & 1)] = hv[j];
      xT[(bi * 32 + d0 + j) * 40 + h] = hv[j];
    }
  }
  __syncthreads();

  const int lane = tid & 63;
  const int l31 = lane & 31;
  const int hi = lane >> 5;
  const int wave = tid >> 6;
  const int n0 = wave * 32;

  const int woff = hi * 1024 + (n0 + l31) * 8;  // per-lane B offset (halfs)
  const half_t* xAl = xA + l31 * 8;
  const half_t* xBl = xB + l31 * 8;

  f32x16 acc[8];
#pragma unroll
  for (int rt = 0; rt < 8; ++rt)
#pragma unroll
    for (int r = 0; r < 16; ++r) acc[rt][r] = 0.f;

  // ================= layer 1 =================
  layer_loop<2, true>(Wp0, xT, xAl, xBl, woff, l31, hi, acc);

  __syncthreads();  // all waves done reading xT before prevT overwrite

  // ---- epilogue 1: relu, cur1 -> prevT (swizzled), d-sum -> out[:, 0:128] ----
#pragma unroll
  for (int rt = 0; rt < 8; ++rt) {
    float s = 0.f;
#pragma unroll
    for (int r = 0; r < 16; ++r) {
      float v = acc[rt][r];
      v = v > 0.f ? v : 0.f;
      s += v;
      int d = (r & 3) + ((r >> 2) << 3) + hi * 4;  // C/D row map (32x32)
      prevT[pswz(rt * 32 + d, n0 + l31)] = (half_t)v;
      acc[rt][r] = 0.f;
    }
    s += __shfl_down(s, 32);
    if (lane < 32) out[(size_t)(b0 + rt) * 256 + n0 + lane] = s;
  }
  __syncthreads();

  // ================= layer 2 =================
  layer_loop<8, false>(Wp1, prevT, xAl, xBl, woff, l31, hi, acc);

  // ---- epilogue 2: relu, d-sum -> out[:, 128:256] ----
#pragma unroll
  for (int rt = 0; rt < 8; ++rt) {
    float s = 0.f;
#pragma unroll
    for (int r = 0; r < 16; ++r) {
      float v = acc[rt][r];
      s += v > 0.f ? v : 0.f;
    }
    s += __shfl_down(s, 32);
    if (lane < 32) out[(size_t)(b0 + rt) * 256 + 128 + n0 + lane] = s;
  }
}

extern "C" void kernel_launch(void* const* d_in, const int* in_sizes, int n_in,
                              void* d_out, int out_size, void* d_ws,
                              size_t ws_size, hipStream_t stream) {
  const float* x0 = (const float*)d_in[0];  // [4096,32,32]
  const float* w0 = (const float*)d_in[1];  // [1,1024,128]
  const float* w1 = (const float*)d_in[2];  // [1,4096,128]
  float* out = (float*)d_out;               // [4096,256]
  char* ws = (char*)d_ws;

  half_t* Wp0 = (half_t*)(ws);                  // 64*2048 f16 = 256 KB
  half_t* Wp1 = (half_t*)(ws + 64 * 2048 * 2);  // 256*2048 f16 = 1 MB

  hipLaunchKernelGGL(prep_w_kernel, dim3(320), dim3(256), 0, stream, w0, w1,
                     Wp0, Wp1);
  hipLaunchKernelGGL(cin_fused_kernel, dim3(512), dim3(256), 0, stream, x0,
                     Wp0, Wp1, out);
}

// Round 10
// 191.761 us; speedup vs baseline: 1.2072x; 1.0465x over previous
//
#include <hip/hip_runtime.h>

// CIN (xDeepFM) fully-fused kernel for MI355X.
// B=4096, F=32, D=32; layer1: K1=1024 -> N=128; layer2: K2=4096 -> N=128.
// GEMM rows=(b,d); A generated in registers: A[(b,d)][h*M+m] = x0[b,h,d]*prev[b,m,d].
// mfma_f32_32x32x16_f16.
// R10: wave tile 4 b x 64 n (rt=4, ct=2). Each generated A-frag (4 pk_mul)
// now feeds TWO MFMAs -> 2 pk_mul/MFMA (was 4). Theory: the R2-R9 plateau
// was vector-ISSUE-port saturation (~14 of 16.1 issue-cyc per MFMA slot);
// halving the A-gen tax drops it to ~62% so the matrix pipe becomes binding.
// Block = 8 b x 128 n (4 waves: b-quad x col-half), LDS 80 KB, grid 512,
// 2 waves/SIMD (acc 128 AGPR + ~100 arch VGPR).

typedef _Float16 half_t;
typedef _Float16 half4v __attribute__((ext_vector_type(4)));
typedef _Float16 half8 __attribute__((ext_vector_type(8)));
typedef float f32x16 __attribute__((ext_vector_type(16)));

// ---- W pack (both filters, one launch): Wp[s][tg][n][8], k=h*M+mc*16+tg*8+j.
__global__ void prep_w_kernel(const float* __restrict__ W0,
                              const float* __restrict__ W1,
                              half_t* __restrict__ Wp0,
                              half_t* __restrict__ Wp1) {
  int gid = blockIdx.x * 256 + threadIdx.x;  // 320*256 threads
  int n = gid & 127;
  int tg = (gid >> 7) & 1;
  int s = gid >> 8;  // 0..319
  const float* W;
  half_t* Wp;
  int M, sl;
  if (s < 64) { W = W0; Wp = Wp0; M = 32; sl = s; }
  else        { W = W1; Wp = Wp1; M = 128; sl = s - 64; }
  int h = sl & 31, mc = sl >> 5;
  int kbase = h * M + mc * 16 + tg * 8;
  half8 v;
#pragma unroll
  for (int j = 0; j < 8; ++j) v[j] = (half_t)W[(size_t)(kbase + j) * 128 + n];
  *(half8*)(Wp + ((size_t)(sl * 2 + tg) * 128 + n) * 8) = v;
}

// swizzled prevT index: logical (row, m) -> halfs offset. 16B-chunk XOR spread.
__device__ __forceinline__ int pswz(int row, int m) {
  return row * 128 + (((m >> 3) ^ (row & 15)) << 3) + (m & 7);
}

__device__ __forceinline__ f32x16 mfma3216(half8 a, half8 b, f32x16 c) {
  return __builtin_amdgcn_mfma_f32_32x32x16_f16(a, b, c, 0, 0, 0);
}

// One CIN layer: MC m-chunks x 32 h. B/x depth-2 ping-pong (register-renamed,
// zero movs). Per gg: 1 ds_read_b128 (x for 4 rt x 2 h), 2 s-steps; per s:
// one shared A-frag per rt feeds both ct B-frags.
template <int MC, bool L1>
__device__ __forceinline__ void layer_loop(const half_t* __restrict__ Wp,
                                           const half_t* __restrict__ psrc,
                                           const half_t* __restrict__ xQw,
                                           int woff0, int woff1, int rowb,
                                           int l31, int hi, f32x16 acc[4][2]) {
  // ping (even gg) / pong (odd gg) register sets
  half8 B0a0 = *(const half8*)(Wp + 0 * 2048 + woff0);
  half8 B0a1 = *(const half8*)(Wp + 0 * 2048 + woff1);
  half8 B1a0 = *(const half8*)(Wp + 1 * 2048 + woff0);
  half8 B1a1 = *(const half8*)(Wp + 1 * 2048 + woff1);
  half8 B0b0 = *(const half8*)(Wp + 2 * 2048 + woff0);
  half8 B0b1 = *(const half8*)(Wp + 2 * 2048 + woff1);
  half8 B1b0 = *(const half8*)(Wp + 3 * 2048 + woff0);
  half8 B1b1 = *(const half8*)(Wp + 3 * 2048 + woff1);
  half8 xqa = *(const half8*)(xQw);
  half8 xqb = *(const half8*)(xQw + 256);

  half8 P[4];
#pragma unroll
  for (int rt = 0; rt < 4; ++rt)
    P[rt] = L1 ? *(const half8*)&psrc[(rowb + rt * 32 + l31) * 40 + hi * 8]
               : *(const half8*)&psrc[pswz(rowb + rt * 32 + l31, hi * 8)];

#pragma unroll 1
  for (int mc = 0; mc < MC; ++mc) {
#pragma unroll 1
    for (int p = 0; p < 8; ++p) {
      const int g0 = mc * 16 + 2 * p;  // even gg (global)
      // ---- even gg: s = 2g0 (B0?), 2g0+1 (B1?); consume ping ----
#pragma unroll
      for (int rt = 0; rt < 4; ++rt) {
        half8 Af = P[rt] * xqa[rt * 2 + 0];
        acc[rt][0] = mfma3216(Af, B0a0, acc[rt][0]);
        acc[rt][1] = mfma3216(Af, B0a1, acc[rt][1]);
      }
#pragma unroll
      for (int rt = 0; rt < 4; ++rt) {
        half8 Af = P[rt] * xqa[rt * 2 + 1];
        acc[rt][0] = mfma3216(Af, B1a0, acc[rt][0]);
        acc[rt][1] = mfma3216(Af, B1a1, acc[rt][1]);
      }
      {  // refill ping for g0+2
        const int sn = (2 * (g0 + 2)) & (MC * 32 - 1);
        B0a0 = *(const half8*)(Wp + (size_t)sn * 2048 + woff0);
        B0a1 = *(const half8*)(Wp + (size_t)sn * 2048 + woff1);
        B1a0 = *(const half8*)(Wp + (size_t)(sn + 1) * 2048 + woff0);
        B1a1 = *(const half8*)(Wp + (size_t)(sn + 1) * 2048 + woff1);
        xqa = *(const half8*)(xQw + ((2 * p + 2) & 15) * 256);
      }
      // ---- odd gg: consume pong ----
#pragma unroll
      for (int rt = 0; rt < 4; ++rt) {
        half8 Af = P[rt] * xqb[rt * 2 + 0];
        acc[rt][0] = mfma3216(Af, B0b0, acc[rt][0]);
        acc[rt][1] = mfma3216(Af, B0b1, acc[rt][1]);
      }
#pragma unroll
      for (int rt = 0; rt < 4; ++rt) {
        half8 Af = P[rt] * xqb[rt * 2 + 1];
        acc[rt][0] = mfma3216(Af, B1b0, acc[rt][0]);
        acc[rt][1] = mfma3216(Af, B1b1, acc[rt][1]);
      }
      {  // refill pong for g0+3
        const int sn = (2 * (g0 + 3)) & (MC * 32 - 1);
        B0b0 = *(const half8*)(Wp + (size_t)sn * 2048 + woff0);
        B0b1 = *(const half8*)(Wp + (size_t)sn * 2048 + woff1);
        B1b0 = *(const half8*)(Wp + (size_t)(sn + 1) * 2048 + woff0);
        B1b1 = *(const half8*)(Wp + (size_t)(sn + 1) * 2048 + woff1);
        xqb = *(const half8*)(xQw + ((2 * p + 3) & 15) * 256);
      }
    }
    if (mc + 1 < MC) {
      const int mn = (mc + 1) * 16;
#pragma unroll
      for (int rt = 0; rt < 4; ++rt)
        P[rt] = L1 ? *(const half8*)&psrc[(rowb + rt * 32 + l31) * 40 + mn +
                                          hi * 8]
                   : *(const half8*)&psrc[pswz(rowb + rt * 32 + l31,
                                               mn + hi * 8)];
    }
  }
}

__global__ __launch_bounds__(256, 2) void cin_fused_kernel(
    const float* __restrict__ x0,    // [4096][32][32] fp32
    const half_t* __restrict__ Wp0,  // 64*2048 halfs
    const half_t* __restrict__ Wp1,  // 256*2048 halfs
    float* __restrict__ out) {       // [4096][256]
  __shared__ half_t xQ[2 * 16 * 32 * 8];  // [quad][hp][d][rtl*2+(h&1)] (16 KB)
  __shared__ half_t prevT[8 * 32 * 128];  // swizzled [bi][d][m] (64 KB); alias xT
  half_t* xT = prevT;                     // [bi*32+d][h], stride 40 halfs

  const int tid = threadIdx.x;
  const int b0 = blockIdx.x * 8;

  // ---- stage x0 -> xQ and xT (8 b = 8192 floats = 2048 float4) ----
  const float4* x4 = (const float4*)(x0 + (size_t)b0 * 1024);
#pragma unroll
  for (int r = 0; r < 8; ++r) {
    int q = r * 256 + tid;
    float4 v = x4[q];
    int e4 = q * 4;
    int bi = e4 >> 10, h = (e4 >> 5) & 31, d0 = e4 & 31;
    half4v hv = {(half_t)v.x, (half_t)v.y, (half_t)v.z, (half_t)v.w};
    const int quad = bi >> 2, rtl = bi & 3;
#pragma unroll
    for (int j = 0; j < 4; ++j) {
      xQ[quad * 4096 + (h >> 1) * 256 + (d0 + j) * 8 + rtl * 2 + (h & 1)] =
          hv[j];
      xT[(bi * 32 + d0 + j) * 40 + h] = hv[j];
    }
  }
  __syncthreads();

  const int lane = tid & 63;
  const int l31 = lane & 31;
  const int hi = lane >> 5;
  const int wave = tid >> 6;
  const int wr = wave >> 1;  // b-quad: b's wr*4 .. wr*4+3
  const int wc = wave & 1;   // col half: n in [wc*64, wc*64+64)

  const int woff0 = hi * 1024 + (wc * 64 + l31) * 8;       // ct=0 B offset
  const int woff1 = hi * 1024 + (wc * 64 + 32 + l31) * 8;  // ct=1 B offset
  const int rowb = wr * 128;                               // P row base
  const half_t* xQw = xQ + wr * 4096 + l31 * 8;

  f32x16 acc[4][2];
#pragma unroll
  for (int rt = 0; rt < 4; ++rt)
#pragma unroll
    for (int ct = 0; ct < 2; ++ct)
#pragma unroll
      for (int r = 0; r < 16; ++r) acc[rt][ct][r] = 0.f;

  // ================= layer 1 =================
  layer_loop<2, true>(Wp0, xT, xQw, woff0, woff1, rowb, l31, hi, acc);

  __syncthreads();  // all waves done reading xT before prevT overwrite

  // ---- epilogue 1: relu, cur1 -> prevT (swizzled), d-sum -> out[:, 0:128] ----
#pragma unroll
  for (int rt = 0; rt < 4; ++rt) {
#pragma unroll
    for (int ct = 0; ct < 2; ++ct) {
      float s = 0.f;
#pragma unroll
      for (int r = 0; r < 16; ++r) {
        float v = acc[rt][ct][r];
        v = v > 0.f ? v : 0.f;
        s += v;
        int d = (r & 3) + ((r >> 2) << 3) + hi * 4;  // C/D row map (32x32)
        prevT[pswz(rowb + rt * 32 + d, wc * 64 + ct * 32 + l31)] = (half_t)v;
        acc[rt][ct][r] = 0.f;
      }
      s += __shfl_down(s, 32);
      if (lane < 32)
        out[(size_t)(b0 + wr * 4 + rt) * 256 + wc * 64 + ct * 32 + lane] = s;
    }
  }
  __syncthreads();

  // ================= layer 2 =================
  layer_loop<8, false>(Wp1, prevT, xQw, woff0, woff1, rowb, l31, hi, acc);

  // ---- epilogue 2: relu, d-sum -> out[:, 128:256] ----
#pragma unroll
  for (int rt = 0; rt < 4; ++rt) {
#pragma unroll
    for (int ct = 0; ct < 2; ++ct) {
      float s = 0.f;
#pragma unroll
      for (int r = 0; r < 16; ++r) {
        float v = acc[rt][ct][r];
        s += v > 0.f ? v : 0.f;
      }
      s += __shfl_down(s, 32);
      if (lane < 32)
        out[(size_t)(b0 + wr * 4 + rt) * 256 + 128 + wc * 64 + ct * 32 +
            lane] = s;
    }
  }
}

extern "C" void kernel_launch(void* const* d_in, const int* in_sizes, int n_in,
                              void* d_out, int out_size, void* d_ws,
                              size_t ws_size, hipStream_t stream) {
  const float* x0 = (const float*)d_in[0];  // [4096,32,32]
  const float* w0 = (const float*)d_in[1];  // [1,1024,128]
  const float* w1 = (const float*)d_in[2];  // [1,4096,128]
  float* out = (float*)d_out;               // [4096,256]
  char* ws = (char*)d_ws;

  half_t* Wp0 = (half_t*)(ws);                  // 64*2048 f16 = 256 KB
  half_t* Wp1 = (half_t*)(ws + 64 * 2048 * 2);  // 256*2048 f16 = 1 MB

  hipLaunchKernelGGL(prep_w_kernel, dim3(320), dim3(256), 0, stream, w0, w1,
                     Wp0, Wp1);
  hipLaunchKernelGGL(cin_fused_kernel, dim3(512), dim3(256), 0, stream, x0,
                     Wp0, Wp1, out);
}